// Round 12
// baseline (453.144 us; speedup 1.0000x reference)
//
#include <hip/hip_runtime.h>
#include <hip/hip_fp16.h>
#include <math.h>
#include <stdint.h>
#include <type_traits>

#define NN   100000
#define EE   1200000
#define GG   128
#define FIN  16
#define HH   64
#define OUTF 5
#define NHID 3

#define CE   4096                       // edges per block in bucket phases
#define EB   ((EE + CE - 1) / CE)       // 293 edge-blocks
#define NBUK ((NN + 511) >> 9)          // 196 buckets of 512 nodes
#define LEN  (NBUK * EB)                // hblk/eoff length

#define SRCMASK 0x03FFFFFFu             // low 26 bits of packed col entry
#define FB_DST 32                       // dsts per fused block

typedef _Float16 f16x8 __attribute__((ext_vector_type(8)));
typedef _Float16 f16x2 __attribute__((ext_vector_type(2)));
typedef float f32x4 __attribute__((ext_vector_type(4)));

#if defined(__has_builtin)
#if __has_builtin(__builtin_amdgcn_fdot2)
#define HAVE_FDOT2 1
#endif
#endif

static __device__ __forceinline__ float dot8_f16(f16x8 a, f16x8 b) {
#ifdef HAVE_FDOT2
  float ds = 0.f;
#pragma unroll
  for (int u = 0; u < 4; u++) {
    f16x2 x = {a[2 * u], a[2 * u + 1]};
    f16x2 y = {b[2 * u], b[2 * u + 1]};
    ds = __builtin_amdgcn_fdot2(x, y, ds, false);
  }
  return ds;
#else
  float ds = 0.f;
#pragma unroll
  for (int u = 0; u < 8; u++) ds += (float)a[u] * (float)b[u];
  return ds;
#endif
}

// ---------------- wave helpers ----------------
static __device__ __forceinline__ float wave_reduce_sum(float p) {
#pragma unroll
  for (int m = 32; m >= 1; m >>= 1) p += __shfl_xor(p, m, 64);
  return p;
}

// ---------------- bucketed CSR build ----------------
__global__ void k_bh(const int* __restrict__ ei, int* __restrict__ hblk) {
  __shared__ int h[NBUK];
  int tid = threadIdx.x, blk = blockIdx.x;
  for (int i = tid; i < NBUK; i += 256) h[i] = 0;
  __syncthreads();
  int base = blk * CE;
  for (int i = tid; i < CE; i += 256) {
    int e = base + i;
    if (e < EE) atomicAdd(&h[ei[EE + e] >> 9], 1);
  }
  __syncthreads();
  for (int i = tid; i < NBUK; i += 256) hblk[i * EB + blk] = h[i];
}

__global__ void k_scan1(const int* __restrict__ in, int* __restrict__ incl,
                        int* __restrict__ bsum, int n) {
  __shared__ int sd[256];
  int t = threadIdx.x, blk = blockIdx.x;
  int base = blk * 1024 + t * 4;
  int v[4];
#pragma unroll
  for (int i = 0; i < 4; i++) v[i] = (base + i < n) ? in[base + i] : 0;
  int s = v[0] + v[1] + v[2] + v[3];
  sd[t] = s;
  __syncthreads();
  for (int off = 1; off < 256; off <<= 1) {
    int x = 0;
    if (t >= off) x = sd[t - off];
    __syncthreads();
    if (t >= off) sd[t] += x;
    __syncthreads();
  }
  int run = sd[t] - s;
#pragma unroll
  for (int i = 0; i < 4; i++) {
    run += v[i];
    if (base + i < n) incl[base + i] = run;
  }
  if (t == 255) bsum[blk] = sd[255];
}

// R26: scan2 folded in — wave 0 computes the 57-entry exclusive prefix of
// bsum via __shfl_up (replaces the single-thread serial k_scan2 kernel:
// 57 dependent global round-trips, ~10-25us of pure serialization).
__global__ void k_eoff(const int* __restrict__ incl, const int* __restrict__ bsum,
                       const int* __restrict__ hblk, int* __restrict__ eoff,
                       int n, int nb) {
  __shared__ int sb[64];
  int tid = threadIdx.x;
  if (tid < 64) {
    int v = (tid < nb) ? bsum[tid] : 0;
    int x = v;
#pragma unroll
    for (int off = 1; off < 64; off <<= 1) {
      int y = __shfl_up(x, off, 64);
      if (tid >= off) x += y;
    }
    sb[tid] = x - v;                   // exclusive prefix
  }
  __syncthreads();
  int t = blockIdx.x * blockDim.x + tid;
  if (t < n) eoff[t] = incl[t] + sb[t / 1024] - hblk[t];
}

__global__ void k_binwrite(const int* __restrict__ ei, const int* __restrict__ eoff,
                           int2* __restrict__ ebuf) {
  __shared__ int cur[NBUK];
  int tid = threadIdx.x, blk = blockIdx.x;
  for (int i = tid; i < NBUK; i += 256) cur[i] = eoff[i * EB + blk];
  __syncthreads();
  int base = blk * CE;
  for (int i = tid; i < CE; i += 256) {
    int e = base + i;
    if (e < EE) {
      int d = ei[EE + e];
      int s = ei[e];
      int p = atomicAdd(&cur[d >> 9], 1);
      ebuf[p] = make_int2(s, d);
    }
  }
}

// merged bdeg2 + binscatter: histogram -> scan -> row_ptr -> cursors ->
// scatter col. col entry packs dst-mod-64 into bits 26..31 (unused by the
// fused kernel, masked off harmlessly); src (<2^26) in low bits.
__global__ void k_bcsr(const int2* __restrict__ ebuf, const int* __restrict__ eoff,
                       int* __restrict__ row_ptr, int* __restrict__ col, int n) {
  __shared__ int dl[512];
  __shared__ int ps[256];
  int b = blockIdx.x, tid = threadIdx.x;
  int d0 = b << 9;
  dl[tid] = 0; dl[tid + 256] = 0;
  __syncthreads();
  int s0 = eoff[b * EB];
  int s1 = (b + 1 < NBUK) ? eoff[(b + 1) * EB] : EE;
  for (int e = s0 + tid; e < s1; e += 256) atomicAdd(&dl[ebuf[e].y - d0], 1);
  __syncthreads();
  int a0 = dl[2 * tid], a1 = dl[2 * tid + 1];
  ps[tid] = a0 + a1;
  __syncthreads();
  for (int off = 1; off < 256; off <<= 1) {
    int x = 0;
    if (tid >= off) x = ps[tid - off];
    __syncthreads();
    if (tid >= off) ps[tid] += x;
    __syncthreads();
  }
  int epair = ps[tid] - (a0 + a1);     // exclusive prefix of this pair
  int r0 = s0 + epair;
  int r1 = r0 + a0;
  int i0 = d0 + 2 * tid;
  if (i0 <= n) row_ptr[i0] = r0;       // covers row_ptr[n] = EE
  if (i0 + 1 <= n) row_ptr[i0 + 1] = r1;
  __syncthreads();
  dl[2 * tid] = r0;                    // reuse histogram LDS as cursors
  dl[2 * tid + 1] = r1;
  __syncthreads();
  for (int e = s0 + tid; e < s1; e += 256) {
    int2 sd = ebuf[e];
    int p = atomicAdd(&dl[sd.y - d0], 1);
    col[p] = (int)(((unsigned)sd.x) | (((unsigned)sd.y & 63u) << 26));
  }
}

// ---------------- projections via MFMA (R25-proven epilogue) ----------------
template <int F, typename TIN>
__global__ __launch_bounds__(256) void k_gemm_mfma(
    const TIN* __restrict__ X,
    const float* __restrict__ Wq, const float* __restrict__ bq,
    const float* __restrict__ Wk, const float* __restrict__ bk,
    const float* __restrict__ Wv, const float* __restrict__ bv,
    const float* __restrict__ Ws, const float* __restrict__ bs,
    __half* __restrict__ qh, __half* __restrict__ kh, __half* __restrict__ vh,
    __half* __restrict__ Bh, int n) {
  constexpr int KH = (F + 31) / 32;
  constexpr int S = KH * 32 + 8;
  constexpr int STG = 64 * S;
  constexpr int OUTL = 4 * 16 * 68;        // 4 waves x private 16x68
  constexpr int LSZ = (STG > OUTL) ? STG : OUTL;
  __shared__ _Float16 xs[LSZ];
  int tid = threadIdx.x;
  int lane = tid & 63;
  int wv = tid >> 6;
  int quad = lane >> 4;
  int li = lane & 15;
  int node0 = blockIdx.x * 64;

  if constexpr (std::is_same<TIN, float>::value) {
    constexpr int F4 = F / 4;
    constexpr int CNT = 64 * F4 / 256;
#pragma unroll
    for (int i = 0; i < CNT; i++) {
      int idx = tid + i * 256;
      int nd = idx / F4;
      int kb = (idx % F4) * 4;
      float4 p;
      if (node0 + nd < n) p = *(const float4*)(X + (size_t)(node0 + nd) * F + kb);
      else p = make_float4(0.f, 0.f, 0.f, 0.f);
      _Float16* d = xs + nd * S + kb;
      d[0] = (_Float16)p.x; d[1] = (_Float16)p.y;
      d[2] = (_Float16)p.z; d[3] = (_Float16)p.w;
    }
    if (F == 16) {  // zero-pad k in [16,32)
      int nd = tid >> 2;
      int kb = 16 + (tid & 3) * 4;
      _Float16* d = xs + nd * S + kb;
      d[0] = 0; d[1] = 0; d[2] = 0; d[3] = 0;
    }
  } else {
    constexpr int F8 = F / 8;
    constexpr int CNT = 64 * F8 / 256;
#pragma unroll
    for (int i = 0; i < CNT; i++) {
      int idx = tid + i * 256;
      int nd = idx / F8;
      int kb = (idx % F8) * 8;
      f16x8 p = {};
      if (node0 + nd < n)
        p = *(const f16x8*)((const _Float16*)X + (size_t)(node0 + nd) * F + kb);
      *(f16x8*)(xs + nd * S + kb) = p;
    }
  }

  const float* W; const float* bias;
  if (wv == 0)      { W = Wq; bias = bq; }
  else if (wv == 1) { W = Wk; bias = bk; }
  else if (wv == 2) { W = Wv; bias = bv; }
  else              { W = Ws; bias = bs; }

  f16x8 bf[4][KH];
#pragma unroll
  for (int ns = 0; ns < 4; ns++)
#pragma unroll
    for (int kh2 = 0; kh2 < KH; kh2++)
#pragma unroll
      for (int j = 0; j < 8; j++) {
        int kidx = kh2 * 32 + quad * 8 + j;
        bf[ns][kh2][j] = (kidx < F)
            ? (_Float16)W[(size_t)kidx * 64 + ns * 16 + li] : (_Float16)0.f;
      }
  float blv[4];
#pragma unroll
  for (int ns = 0; ns < 4; ns++) blv[ns] = bias[ns * 16 + li];

  __syncthreads();

  f16x8 af[4][KH];
#pragma unroll
  for (int ms = 0; ms < 4; ms++)
#pragma unroll
    for (int kh2 = 0; kh2 < KH; kh2++)
      af[ms][kh2] = *(const f16x8*)(xs + (ms * 16 + li) * S + kh2 * 32 + quad * 8);

  f32x4 acc[4][4];
#pragma unroll
  for (int ms = 0; ms < 4; ms++)
#pragma unroll
    for (int ns = 0; ns < 4; ns++) {
      float b = blv[ns];
      acc[ms][ns] = (f32x4){b, b, b, b};
    }
#pragma unroll
  for (int kh2 = 0; kh2 < KH; kh2++)
#pragma unroll
    for (int ms = 0; ms < 4; ms++)
#pragma unroll
      for (int ns = 0; ns < 4; ns++)
        acc[ms][ns] = __builtin_amdgcn_mfma_f32_16x16x32_f16(
            af[ms][kh2], bf[ns][kh2], acc[ms][ns], 0, 0, 0);

  __syncthreads();   // end of xs (af) reads; out-staging regions now safe

  __half* outh = (wv == 0) ? qh : (wv == 1) ? kh : (wv == 2) ? vh : Bh;
  _Float16* ob = xs + wv * (16 * 68);   // per-wave private region
#pragma unroll
  for (int ms = 0; ms < 4; ms++) {
#pragma unroll
    for (int ns = 0; ns < 4; ns++)
#pragma unroll
      for (int r = 0; r < 4; r++)
        ob[(quad * 4 + r) * 68 + ns * 16 + li] = (_Float16)acc[ms][ns][r];
#pragma unroll
    for (int it = 0; it < 2; it++) {
      int c = lane + it * 64;
      int row = c >> 3, j = c & 7;
      int node = node0 + ms * 16 + row;
      if (node < n)
        *(f16x8*)((_Float16*)outh + (size_t)node * 64 + j * 8) =
            *(const f16x8*)(ob + row * 68 + j * 8);
    }
  }
}

// ---------------- fused attention, phase-split + x4 unroll (R26) ------------
// R24 structure (2 dsts per 8-lane group, q+acc in registers, K-pass /
// barrier / V-pass phase split for L2 stream locality). R26: both passes
// unrolled to 4 independent edges per iteration — kh+vh (25.6MB) is
// L3-resident, so the kernel is LATENCY-bound on L3 hits; 4 outstanding
// gathers per lane doubles memory-level parallelism vs the pair loop.
__global__ __launch_bounds__(128) void k_fused(
    const __half* __restrict__ qh, const __half* __restrict__ kh,
    const __half* __restrict__ vh, const int* __restrict__ row_ptr,
    const int* __restrict__ col, __half* __restrict__ Bh, int n) {
  __shared__ int ws[1024];
  __shared__ float pw[1024];
  __shared__ int rpl[FB_DST + 1];
  int tid = threadIdx.x;
  int d0 = blockIdx.x * FB_DST;
  int ndst = n - d0; if (ndst > FB_DST) ndst = FB_DST;

  if (tid < FB_DST + 1) {
    int dd = d0 + tid; if (dd > n) dd = n;
    rpl[tid] = row_ptr[dd];
  }
  __syncthreads();
  int e0 = rpl[0], e1 = rpl[ndst];

  int g = tid >> 3, aj = tid & 7;     // 16 groups x 8 lanes

  f16x8 qv[2] = {};
  float acc[2][8];
  float den[2];
#pragma unroll
  for (int t = 0; t < 2; t++) {
    den[t] = 0.f;
#pragma unroll
    for (int u = 0; u < 8; u++) acc[t][u] = 0.f;
    int dl = 2 * g + t;
    if (dl < ndst)
      qv[t] = *(const f16x8*)((const _Float16*)qh + (size_t)(d0 + dl) * 64 + aj * 8);
  }

  for (int c0 = e0; c0 < e1; c0 += 1024) {
    int cn = e1 - c0; if (cn > 1024) cn = 1024;
#pragma unroll
    for (int s = 0; s < 8; s++) {      // stage col chunk, coalesced
      int i = tid + s * 128;
      if (i < cn) ws[i] = col[c0 + i];
    }
    __syncthreads();

    // ---- K-pass: k-gathers only -> pe, den, pw (x4 unroll) ----
#pragma unroll
    for (int t = 0; t < 2; t++) {
      int dl = 2 * g + t;
      if (dl < ndst) {
        int lo = rpl[dl];     if (lo < c0) lo = c0;
        int hi = rpl[dl + 1]; int ce = c0 + cn; if (hi > ce) hi = ce;
        int i = lo - c0, iend = hi - c0;
        for (; i + 4 <= iend; i += 4) {
          int s0 = ws[i] & (int)SRCMASK;
          int s1 = ws[i + 1] & (int)SRCMASK;
          int s2 = ws[i + 2] & (int)SRCMASK;
          int s3 = ws[i + 3] & (int)SRCMASK;
          f16x8 k0 = *(const f16x8*)((const _Float16*)kh + (size_t)s0 * 64 + aj * 8);
          f16x8 k1 = *(const f16x8*)((const _Float16*)kh + (size_t)s1 * 64 + aj * 8);
          f16x8 k2 = *(const f16x8*)((const _Float16*)kh + (size_t)s2 * 64 + aj * 8);
          f16x8 k3 = *(const f16x8*)((const _Float16*)kh + (size_t)s3 * 64 + aj * 8);
          float da = dot8_f16(qv[t], k0);
          float db = dot8_f16(qv[t], k1);
          float dc = dot8_f16(qv[t], k2);
          float dd = dot8_f16(qv[t], k3);
          da += __shfl_xor(da, 1, 64); db += __shfl_xor(db, 1, 64);
          dc += __shfl_xor(dc, 1, 64); dd += __shfl_xor(dd, 1, 64);
          da += __shfl_xor(da, 2, 64); db += __shfl_xor(db, 2, 64);
          dc += __shfl_xor(dc, 2, 64); dd += __shfl_xor(dd, 2, 64);
          da += __shfl_xor(da, 4, 64); db += __shfl_xor(db, 4, 64);
          dc += __shfl_xor(dc, 4, 64); dd += __shfl_xor(dd, 4, 64);
          float pa = __expf(fminf(da * 0.125f, 60.f));   // 1/sqrt(64)
          float pb = __expf(fminf(db * 0.125f, 60.f));
          float pc = __expf(fminf(dc * 0.125f, 60.f));
          float pd = __expf(fminf(dd * 0.125f, 60.f));
          den[t] += (pa + pb) + (pc + pd);
          if (aj == 0) { pw[i] = pa; pw[i + 1] = pb; pw[i + 2] = pc; pw[i + 3] = pd; }
        }
        for (; i < iend; i++) {
          int s0 = ws[i] & (int)SRCMASK;
          f16x8 k0 = *(const f16x8*)((const _Float16*)kh + (size_t)s0 * 64 + aj * 8);
          float da = dot8_f16(qv[t], k0);
          da += __shfl_xor(da, 1, 64);
          da += __shfl_xor(da, 2, 64);
          da += __shfl_xor(da, 4, 64);
          float pa = __expf(fminf(da * 0.125f, 60.f));
          den[t] += pa;
          if (aj == 0) pw[i] = pa;
        }
      }
    }
    __syncthreads();   // phase the gather streams (locality, not correctness)

    // ---- V-pass: v-gathers only; pw broadcast reads; fma (x4 unroll) ----
#pragma unroll
    for (int t = 0; t < 2; t++) {
      int dl = 2 * g + t;
      if (dl < ndst) {
        int lo = rpl[dl];     if (lo < c0) lo = c0;
        int hi = rpl[dl + 1]; int ce = c0 + cn; if (hi > ce) hi = ce;
        int i = lo - c0, iend = hi - c0;
        for (; i + 4 <= iend; i += 4) {
          int s0 = ws[i] & (int)SRCMASK;
          int s1 = ws[i + 1] & (int)SRCMASK;
          int s2 = ws[i + 2] & (int)SRCMASK;
          int s3 = ws[i + 3] & (int)SRCMASK;
          float pa = pw[i], pb = pw[i + 1], pc = pw[i + 2], pd = pw[i + 3];
          f16x8 v0 = *(const f16x8*)((const _Float16*)vh + (size_t)s0 * 64 + aj * 8);
          f16x8 v1 = *(const f16x8*)((const _Float16*)vh + (size_t)s1 * 64 + aj * 8);
          f16x8 v2 = *(const f16x8*)((const _Float16*)vh + (size_t)s2 * 64 + aj * 8);
          f16x8 v3 = *(const f16x8*)((const _Float16*)vh + (size_t)s3 * 64 + aj * 8);
#pragma unroll
          for (int u = 0; u < 8; u++) {
            acc[t][u] = fmaf(pa, (float)v0[u], acc[t][u]);
            acc[t][u] = fmaf(pb, (float)v1[u], acc[t][u]);
            acc[t][u] = fmaf(pc, (float)v2[u], acc[t][u]);
            acc[t][u] = fmaf(pd, (float)v3[u], acc[t][u]);
          }
        }
        for (; i < iend; i++) {
          int s0 = ws[i] & (int)SRCMASK;
          float pa = pw[i];
          f16x8 v0 = *(const f16x8*)((const _Float16*)vh + (size_t)s0 * 64 + aj * 8);
#pragma unroll
          for (int u = 0; u < 8; u++)
            acc[t][u] = fmaf(pa, (float)v0[u], acc[t][u]);
        }
      }
    }
    __syncthreads();   // before next chunk overwrites ws/pw
  }

  // write out (B pre-holds the skip term); 8 lanes cover one dst row
#pragma unroll
  for (int t = 0; t < 2; t++) {
    int dl = 2 * g + t;
    if (dl < ndst) {
      _Float16* bp = (_Float16*)Bh + (size_t)(d0 + dl) * 64 + aj * 8;
      f16x8 old = *(const f16x8*)bp;
      float inv = 1.f / (den[t] + 1e-16f);
      f16x8 o;
#pragma unroll
      for (int u = 0; u < 8; u++)
        o[u] = (_Float16)((float)old[u] + acc[t][u] * inv);
      *(f16x8*)bp = o;
    }
  }
}

// ---------------- pooling ----------------
__global__ __launch_bounds__(256) void k_pool(
    const __half* __restrict__ H, const int* __restrict__ batch,
    float* __restrict__ pooled, int* __restrict__ cnt, int n) {
  int lane = threadIdx.x & 63;
  int w = threadIdx.x >> 6;
  int n0 = blockIdx.x * 64 + w * 16;
  float acc = 0.f;
  int cur = -1, nc = 0;
  for (int i = 0; i < 16; i++) {
    int node = n0 + i;
    if (node >= n) break;
    int g = batch[node];
    if (g != cur) {
      if (cur >= 0) {
        atomicAdd(&pooled[cur * 64 + lane], acc);
        if (lane == 0) atomicAdd(&cnt[cur], nc);
      }
      cur = g;
      acc = 0.f;
      nc = 0;
    }
    acc += __half2float(H[(size_t)node * 64 + lane]);
    nc++;
  }
  if (cur >= 0) {
    atomicAdd(&pooled[cur * 64 + lane], acc);
    if (lane == 0) atomicAdd(&cnt[cur], nc);
  }
}

__global__ void k_out(const float* __restrict__ pooled, const int* __restrict__ cnt,
                      const float* __restrict__ Wf, const float* __restrict__ bf,
                      float* __restrict__ out) {
  int g = blockIdx.x;
  int lane = threadIdx.x;
  int c = cnt[g];
  float cf = (float)(c > 1 ? c : 1);
  float mean = pooled[g * 64 + lane] / cf;
#pragma unroll
  for (int o = 0; o < OUTF; o++) {
    float p = wave_reduce_sum(mean * Wf[lane * OUTF + o]);
    if (lane == 0) out[g * OUTF + o] = p + bf[o];
  }
}

// ---------------- launch ----------------
extern "C" void kernel_launch(void* const* d_in, const int* in_sizes, int n_in,
                              void* d_out, int out_size, void* d_ws, size_t ws_size,
                              hipStream_t stream) {
  const float* x   = (const float*)d_in[0];
  const int* ei    = (const int*)d_in[1];
  const int* batch = (const int*)d_in[2];
  const float *Wq0 = (const float*)d_in[3],  *bq0 = (const float*)d_in[4];
  const float *Wk0 = (const float*)d_in[5],  *bk0 = (const float*)d_in[6];
  const float *Wv0 = (const float*)d_in[7],  *bv0 = (const float*)d_in[8];
  const float *Ws0 = (const float*)d_in[9],  *bs0 = (const float*)d_in[10];
  const float *Wqh = (const float*)d_in[11], *bqh = (const float*)d_in[12];
  const float *Wkh = (const float*)d_in[13], *bkh = (const float*)d_in[14];
  const float *Wvh = (const float*)d_in[15], *bvh = (const float*)d_in[16];
  const float *Wsh = (const float*)d_in[17], *bsh = (const float*)d_in[18];
  const float *Wf  = (const float*)d_in[19], *bf  = (const float*)d_in[20];

  __half* qh = (__half*)d_ws;
  __half* kh = qh + (size_t)NN * 64;
  __half* vh = kh + (size_t)NN * 64;
  __half* B0 = vh + (size_t)NN * 64;
  __half* B1 = B0 + (size_t)NN * 64;
  float* pooled = (float*)(B1 + (size_t)NN * 64);
  int* cnt     = (int*)(pooled + GG * 64);
  int* row_ptr = cnt + GG;
  int* col     = row_ptr + NN + 2;
  int* hblk    = col + EE;
  int* incl2   = hblk + LEN;
  int* bsum2   = incl2 + LEN;
  int* boff2   = bsum2 + 128;
  int* eoff    = boff2 + 128;
  int2* ebuf   = (int2*)((((uintptr_t)(eoff + LEN)) + 15) & ~(uintptr_t)15);

  hipMemsetAsync(pooled, 0, (GG * 64 + GG) * sizeof(float), stream);

  // bucketed CSR build (once per call; reused by all 4 layers)
  k_bh<<<EB, 256, 0, stream>>>(ei, hblk);
  int nb2 = (LEN + 1023) / 1024;
  k_scan1<<<nb2, 256, 0, stream>>>(hblk, incl2, bsum2, LEN);
  k_eoff<<<(LEN + 255) / 256, 256, 0, stream>>>(incl2, bsum2, hblk, eoff, LEN, nb2);
  k_binwrite<<<EB, 256, 0, stream>>>(ei, eoff, ebuf);
  k_bcsr<<<NBUK, 256, 0, stream>>>(ebuf, eoff, row_ptr, col, NN);

  int gg = (NN + 63) / 64;
  int ga = (NN + FB_DST - 1) / FB_DST;  // 32 dsts per block, 128 threads

  // layer 0 (F_IN=16, fp32 input)
  k_gemm_mfma<FIN, float><<<gg, 256, 0, stream>>>(
      x, Wq0, bq0, Wk0, bk0, Wv0, bv0, Ws0, bs0, qh, kh, vh, B0, NN);
  k_fused<<<ga, 128, 0, stream>>>(qh, kh, vh, row_ptr, col, B0, NN);

  // hidden layers (H=64, fp16 h), ping-pong B0 <-> B1
  const __half* hin = B0;
  __half* hout = B1;
  for (int i = 0; i < NHID; i++) {
    k_gemm_mfma<HH, __half><<<gg, 256, 0, stream>>>(
        hin, Wqh + i * 4096, bqh + i * 64,
        Wkh + i * 4096, bkh + i * 64,
        Wvh + i * 4096, bvh + i * 64,
        Wsh + i * 4096, bsh + i * 64,
        qh, kh, vh, hout, NN);
    k_fused<<<ga, 128, 0, stream>>>(qh, kh, vh, row_ptr, col, hout, NN);
    __half* t = (__half*)hin; hin = hout; hout = t;
  }

  k_pool<<<(NN + 63) / 64, 256, 0, stream>>>(hin, batch, pooled, cnt, NN);
  k_out<<<GG, 64, 0, stream>>>(pooled, cnt, Wf, bf, (float*)d_out);
}

// Round 13
// 432.951 us; speedup vs baseline: 1.0466x; 1.0466x over previous
//
#include <hip/hip_runtime.h>
#include <hip/hip_fp16.h>
#include <math.h>
#include <stdint.h>
#include <type_traits>

#define NN   100000
#define EE   1200000
#define GG   128
#define FIN  16
#define HH   64
#define OUTF 5
#define NHID 3

#define CE   4096                       // edges per block in bucket phases
#define EB   ((EE + CE - 1) / CE)       // 293 edge-blocks
#define NBUK ((NN + 511) >> 9)          // 196 buckets of 512 nodes
#define LEN  (NBUK * EB)                // hblk/eoff length

#define SRCMASK 0x03FFFFFFu             // low 26 bits of packed col entry
#define FB_DST 32                       // dsts per fused block

typedef _Float16 f16x8 __attribute__((ext_vector_type(8)));
typedef _Float16 f16x2 __attribute__((ext_vector_type(2)));
typedef float f32x4 __attribute__((ext_vector_type(4)));

#if defined(__has_builtin)
#if __has_builtin(__builtin_amdgcn_fdot2)
#define HAVE_FDOT2 1
#endif
#endif

static __device__ __forceinline__ float dot8_f16(f16x8 a, f16x8 b) {
#ifdef HAVE_FDOT2
  float ds = 0.f;
#pragma unroll
  for (int u = 0; u < 4; u++) {
    f16x2 x = {a[2 * u], a[2 * u + 1]};
    f16x2 y = {b[2 * u], b[2 * u + 1]};
    ds = __builtin_amdgcn_fdot2(x, y, ds, false);
  }
  return ds;
#else
  float ds = 0.f;
#pragma unroll
  for (int u = 0; u < 8; u++) ds += (float)a[u] * (float)b[u];
  return ds;
#endif
}

// ---------------- wave helpers ----------------
static __device__ __forceinline__ float wave_reduce_sum(float p) {
#pragma unroll
  for (int m = 32; m >= 1; m >>= 1) p += __shfl_xor(p, m, 64);
  return p;
}

// ---------------- bucketed CSR build ----------------
__global__ void k_bh(const int* __restrict__ ei, int* __restrict__ hblk) {
  __shared__ int h[NBUK];
  int tid = threadIdx.x, blk = blockIdx.x;
  for (int i = tid; i < NBUK; i += 256) h[i] = 0;
  __syncthreads();
  int base = blk * CE;
  for (int i = tid; i < CE; i += 256) {
    int e = base + i;
    if (e < EE) atomicAdd(&h[ei[EE + e] >> 9], 1);
  }
  __syncthreads();
  for (int i = tid; i < NBUK; i += 256) hblk[i * EB + blk] = h[i];
}

__global__ void k_scan1(const int* __restrict__ in, int* __restrict__ incl,
                        int* __restrict__ bsum, int n) {
  __shared__ int sd[256];
  int t = threadIdx.x, blk = blockIdx.x;
  int base = blk * 1024 + t * 4;
  int v[4];
#pragma unroll
  for (int i = 0; i < 4; i++) v[i] = (base + i < n) ? in[base + i] : 0;
  int s = v[0] + v[1] + v[2] + v[3];
  sd[t] = s;
  __syncthreads();
  for (int off = 1; off < 256; off <<= 1) {
    int x = 0;
    if (t >= off) x = sd[t - off];
    __syncthreads();
    if (t >= off) sd[t] += x;
    __syncthreads();
  }
  int run = sd[t] - s;
#pragma unroll
  for (int i = 0; i < 4; i++) {
    run += v[i];
    if (base + i < n) incl[base + i] = run;
  }
  if (t == 255) bsum[blk] = sd[255];
}

// scan2 folded in (R26-keeper): wave 0 computes the 57-entry exclusive
// prefix of bsum via __shfl_up — replaces the serial k_scan2 dispatch.
__global__ void k_eoff(const int* __restrict__ incl, const int* __restrict__ bsum,
                       const int* __restrict__ hblk, int* __restrict__ eoff,
                       int n, int nb) {
  __shared__ int sb[64];
  int tid = threadIdx.x;
  if (tid < 64) {
    int v = (tid < nb) ? bsum[tid] : 0;
    int x = v;
#pragma unroll
    for (int off = 1; off < 64; off <<= 1) {
      int y = __shfl_up(x, off, 64);
      if (tid >= off) x += y;
    }
    sb[tid] = x - v;                   // exclusive prefix
  }
  __syncthreads();
  int t = blockIdx.x * blockDim.x + tid;
  if (t < n) eoff[t] = incl[t] + sb[t / 1024] - hblk[t];
}

__global__ void k_binwrite(const int* __restrict__ ei, const int* __restrict__ eoff,
                           int2* __restrict__ ebuf) {
  __shared__ int cur[NBUK];
  int tid = threadIdx.x, blk = blockIdx.x;
  for (int i = tid; i < NBUK; i += 256) cur[i] = eoff[i * EB + blk];
  __syncthreads();
  int base = blk * CE;
  for (int i = tid; i < CE; i += 256) {
    int e = base + i;
    if (e < EE) {
      int d = ei[EE + e];
      int s = ei[e];
      int p = atomicAdd(&cur[d >> 9], 1);
      ebuf[p] = make_int2(s, d);
    }
  }
}

// merged bdeg2 + binscatter: histogram -> scan -> row_ptr -> cursors ->
// scatter col. col entry packs dst-mod-64 into bits 26..31 (unused by the
// fused kernel, masked off harmlessly); src (<2^26) in low bits.
__global__ void k_bcsr(const int2* __restrict__ ebuf, const int* __restrict__ eoff,
                       int* __restrict__ row_ptr, int* __restrict__ col, int n) {
  __shared__ int dl[512];
  __shared__ int ps[256];
  int b = blockIdx.x, tid = threadIdx.x;
  int d0 = b << 9;
  dl[tid] = 0; dl[tid + 256] = 0;
  __syncthreads();
  int s0 = eoff[b * EB];
  int s1 = (b + 1 < NBUK) ? eoff[(b + 1) * EB] : EE;
  for (int e = s0 + tid; e < s1; e += 256) atomicAdd(&dl[ebuf[e].y - d0], 1);
  __syncthreads();
  int a0 = dl[2 * tid], a1 = dl[2 * tid + 1];
  ps[tid] = a0 + a1;
  __syncthreads();
  for (int off = 1; off < 256; off <<= 1) {
    int x = 0;
    if (tid >= off) x = ps[tid - off];
    __syncthreads();
    if (tid >= off) ps[tid] += x;
    __syncthreads();
  }
  int epair = ps[tid] - (a0 + a1);     // exclusive prefix of this pair
  int r0 = s0 + epair;
  int r1 = r0 + a0;
  int i0 = d0 + 2 * tid;
  if (i0 <= n) row_ptr[i0] = r0;       // covers row_ptr[n] = EE
  if (i0 + 1 <= n) row_ptr[i0 + 1] = r1;
  __syncthreads();
  dl[2 * tid] = r0;                    // reuse histogram LDS as cursors
  dl[2 * tid + 1] = r1;
  __syncthreads();
  for (int e = s0 + tid; e < s1; e += 256) {
    int2 sd = ebuf[e];
    int p = atomicAdd(&dl[sd.y - d0], 1);
    col[p] = (int)(((unsigned)sd.x) | (((unsigned)sd.y & 63u) << 26));
  }
}

// ---------------- projections via MFMA (R27: 2 node-tiles per block) --------
// Core unchanged (R20-proven MFMA + R25 per-wave LDS out-staging). R27:
// each block processes 128 nodes as two 64-node tiles, REUSING the bf/blv
// weight fragments — halves the per-block weight-load cost (64 strided
// scalar loads/lane) and the grid (782 blocks), amortizing the dominant
// non-MFMA term. Barrier pair between tiles sequences xs reuse.
template <int F, typename TIN>
__global__ __launch_bounds__(256) void k_gemm_mfma(
    const TIN* __restrict__ X,
    const float* __restrict__ Wq, const float* __restrict__ bq,
    const float* __restrict__ Wk, const float* __restrict__ bk,
    const float* __restrict__ Wv, const float* __restrict__ bv,
    const float* __restrict__ Ws, const float* __restrict__ bs,
    __half* __restrict__ qh, __half* __restrict__ kh, __half* __restrict__ vh,
    __half* __restrict__ Bh, int n) {
  constexpr int KH = (F + 31) / 32;
  constexpr int S = KH * 32 + 8;
  constexpr int STG = 64 * S;
  constexpr int OUTL = 4 * 16 * 68;        // 4 waves x private 16x68
  constexpr int LSZ = (STG > OUTL) ? STG : OUTL;
  __shared__ _Float16 xs[LSZ];
  int tid = threadIdx.x;
  int lane = tid & 63;
  int wv = tid >> 6;
  int quad = lane >> 4;
  int li = lane & 15;
  int nbase = blockIdx.x * 128;

  auto stage_tile = [&](int node0) {
    if constexpr (std::is_same<TIN, float>::value) {
      constexpr int F4 = F / 4;
      constexpr int CNT = 64 * F4 / 256;
#pragma unroll
      for (int i = 0; i < CNT; i++) {
        int idx = tid + i * 256;
        int nd = idx / F4;
        int kb = (idx % F4) * 4;
        float4 p;
        if (node0 + nd < n) p = *(const float4*)(X + (size_t)(node0 + nd) * F + kb);
        else p = make_float4(0.f, 0.f, 0.f, 0.f);
        _Float16* d = xs + nd * S + kb;
        d[0] = (_Float16)p.x; d[1] = (_Float16)p.y;
        d[2] = (_Float16)p.z; d[3] = (_Float16)p.w;
      }
      if (F == 16) {  // zero-pad k in [16,32)
        int nd = tid >> 2;
        int kb = 16 + (tid & 3) * 4;
        _Float16* d = xs + nd * S + kb;
        d[0] = 0; d[1] = 0; d[2] = 0; d[3] = 0;
      }
    } else {
      constexpr int F8 = F / 8;
      constexpr int CNT = 64 * F8 / 256;
#pragma unroll
      for (int i = 0; i < CNT; i++) {
        int idx = tid + i * 256;
        int nd = idx / F8;
        int kb = (idx % F8) * 8;
        f16x8 p = {};
        if (node0 + nd < n)
          p = *(const f16x8*)((const _Float16*)X + (size_t)(node0 + nd) * F + kb);
        *(f16x8*)(xs + nd * S + kb) = p;
      }
    }
  };

  stage_tile(nbase);

  const float* W; const float* bias;
  if (wv == 0)      { W = Wq; bias = bq; }
  else if (wv == 1) { W = Wk; bias = bk; }
  else if (wv == 2) { W = Wv; bias = bv; }
  else              { W = Ws; bias = bs; }

  f16x8 bf[4][KH];
#pragma unroll
  for (int ns = 0; ns < 4; ns++)
#pragma unroll
    for (int kh2 = 0; kh2 < KH; kh2++)
#pragma unroll
      for (int j = 0; j < 8; j++) {
        int kidx = kh2 * 32 + quad * 8 + j;
        bf[ns][kh2][j] = (kidx < F)
            ? (_Float16)W[(size_t)kidx * 64 + ns * 16 + li] : (_Float16)0.f;
      }
  float blv[4];
#pragma unroll
  for (int ns = 0; ns < 4; ns++) blv[ns] = bias[ns * 16 + li];

  __syncthreads();

  __half* outh = (wv == 0) ? qh : (wv == 1) ? kh : (wv == 2) ? vh : Bh;
  _Float16* ob = xs + wv * (16 * 68);   // per-wave private out-stage region

#pragma unroll
  for (int tl = 0; tl < 2; tl++) {
    int node0 = nbase + tl * 64;

    f16x8 af[4][KH];
#pragma unroll
    for (int ms = 0; ms < 4; ms++)
#pragma unroll
      for (int kh2 = 0; kh2 < KH; kh2++)
        af[ms][kh2] = *(const f16x8*)(xs + (ms * 16 + li) * S + kh2 * 32 + quad * 8);

    f32x4 acc[4][4];
#pragma unroll
    for (int ms = 0; ms < 4; ms++)
#pragma unroll
      for (int ns = 0; ns < 4; ns++) {
        float b = blv[ns];
        acc[ms][ns] = (f32x4){b, b, b, b};
      }
#pragma unroll
    for (int kh2 = 0; kh2 < KH; kh2++)
#pragma unroll
      for (int ms = 0; ms < 4; ms++)
#pragma unroll
        for (int ns = 0; ns < 4; ns++)
          acc[ms][ns] = __builtin_amdgcn_mfma_f32_16x16x32_f16(
              af[ms][kh2], bf[ns][kh2], acc[ms][ns], 0, 0, 0);

    __syncthreads();   // all waves done reading xs; safe to out-stage

#pragma unroll
    for (int ms = 0; ms < 4; ms++) {
#pragma unroll
      for (int ns = 0; ns < 4; ns++)
#pragma unroll
        for (int r = 0; r < 4; r++)
          ob[(quad * 4 + r) * 68 + ns * 16 + li] = (_Float16)acc[ms][ns][r];
#pragma unroll
      for (int it = 0; it < 2; it++) {
        int c = lane + it * 64;
        int row = c >> 3, j = c & 7;
        int node = node0 + ms * 16 + row;
        if (node < n)
          *(f16x8*)((_Float16*)outh + (size_t)node * 64 + j * 8) =
              *(const f16x8*)(ob + row * 68 + j * 8);
      }
    }

    if (tl == 0) {
      __syncthreads();             // out-stage LDS reads done block-wide
      stage_tile(nbase + 64);      // restage xs for tile 1
      __syncthreads();
    }
  }
}

// ---------------- fused attention, phase-split pair-unroll (R24-exact) ------
// Best-measured structure (44.6us): 2 dsts per 8-lane group, q+acc in
// registers, K-pass / barrier / V-pass phase split (L2 sees one array at
// a time), pair unroll. R26's x4 unroll regressed (VGPR/schedule) — kept
// at x2.
__global__ __launch_bounds__(128) void k_fused(
    const __half* __restrict__ qh, const __half* __restrict__ kh,
    const __half* __restrict__ vh, const int* __restrict__ row_ptr,
    const int* __restrict__ col, __half* __restrict__ Bh, int n) {
  __shared__ int ws[1024];
  __shared__ float pw[1024];
  __shared__ int rpl[FB_DST + 1];
  int tid = threadIdx.x;
  int d0 = blockIdx.x * FB_DST;
  int ndst = n - d0; if (ndst > FB_DST) ndst = FB_DST;

  if (tid < FB_DST + 1) {
    int dd = d0 + tid; if (dd > n) dd = n;
    rpl[tid] = row_ptr[dd];
  }
  __syncthreads();
  int e0 = rpl[0], e1 = rpl[ndst];

  int g = tid >> 3, aj = tid & 7;     // 16 groups x 8 lanes

  f16x8 qv[2] = {};
  float acc[2][8];
  float den[2];
#pragma unroll
  for (int t = 0; t < 2; t++) {
    den[t] = 0.f;
#pragma unroll
    for (int u = 0; u < 8; u++) acc[t][u] = 0.f;
    int dl = 2 * g + t;
    if (dl < ndst)
      qv[t] = *(const f16x8*)((const _Float16*)qh + (size_t)(d0 + dl) * 64 + aj * 8);
  }

  for (int c0 = e0; c0 < e1; c0 += 1024) {
    int cn = e1 - c0; if (cn > 1024) cn = 1024;
#pragma unroll
    for (int s = 0; s < 8; s++) {      // stage col chunk, coalesced
      int i = tid + s * 128;
      if (i < cn) ws[i] = col[c0 + i];
    }
    __syncthreads();

    // ---- K-pass: k-gathers only -> pe, den, pw ----
#pragma unroll
    for (int t = 0; t < 2; t++) {
      int dl = 2 * g + t;
      if (dl < ndst) {
        int lo = rpl[dl];     if (lo < c0) lo = c0;
        int hi = rpl[dl + 1]; int ce = c0 + cn; if (hi > ce) hi = ce;
        int i = lo - c0, iend = hi - c0;
        for (; i + 2 <= iend; i += 2) {
          int s0 = ws[i] & (int)SRCMASK;
          int s1 = ws[i + 1] & (int)SRCMASK;
          f16x8 k0 = *(const f16x8*)((const _Float16*)kh + (size_t)s0 * 64 + aj * 8);
          f16x8 k1 = *(const f16x8*)((const _Float16*)kh + (size_t)s1 * 64 + aj * 8);
          float da = dot8_f16(qv[t], k0);
          float db = dot8_f16(qv[t], k1);
          da += __shfl_xor(da, 1, 64); db += __shfl_xor(db, 1, 64);
          da += __shfl_xor(da, 2, 64); db += __shfl_xor(db, 2, 64);
          da += __shfl_xor(da, 4, 64); db += __shfl_xor(db, 4, 64);
          float pa = __expf(fminf(da * 0.125f, 60.f));   // 1/sqrt(64)
          float pb = __expf(fminf(db * 0.125f, 60.f));
          den[t] += pa + pb;
          if (aj == 0) { pw[i] = pa; pw[i + 1] = pb; }
        }
        if (i < iend) {
          int s0 = ws[i] & (int)SRCMASK;
          f16x8 k0 = *(const f16x8*)((const _Float16*)kh + (size_t)s0 * 64 + aj * 8);
          float da = dot8_f16(qv[t], k0);
          da += __shfl_xor(da, 1, 64);
          da += __shfl_xor(da, 2, 64);
          da += __shfl_xor(da, 4, 64);
          float pa = __expf(fminf(da * 0.125f, 60.f));
          den[t] += pa;
          if (aj == 0) pw[i] = pa;
        }
      }
    }
    __syncthreads();   // phase the gather streams (locality, not correctness)

    // ---- V-pass: v-gathers only; pw broadcast reads; fma into registers ----
#pragma unroll
    for (int t = 0; t < 2; t++) {
      int dl = 2 * g + t;
      if (dl < ndst) {
        int lo = rpl[dl];     if (lo < c0) lo = c0;
        int hi = rpl[dl + 1]; int ce = c0 + cn; if (hi > ce) hi = ce;
        int i = lo - c0, iend = hi - c0;
        for (; i + 2 <= iend; i += 2) {
          int s0 = ws[i] & (int)SRCMASK;
          int s1 = ws[i + 1] & (int)SRCMASK;
          float pa = pw[i], pb = pw[i + 1];
          f16x8 v0 = *(const f16x8*)((const _Float16*)vh + (size_t)s0 * 64 + aj * 8);
          f16x8 v1 = *(const f16x8*)((const _Float16*)vh + (size_t)s1 * 64 + aj * 8);
#pragma unroll
          for (int u = 0; u < 8; u++) {
            acc[t][u] = fmaf(pa, (float)v0[u], acc[t][u]);
            acc[t][u] = fmaf(pb, (float)v1[u], acc[t][u]);
          }
        }
        if (i < iend) {
          int s0 = ws[i] & (int)SRCMASK;
          float pa = pw[i];
          f16x8 v0 = *(const f16x8*)((const _Float16*)vh + (size_t)s0 * 64 + aj * 8);
#pragma unroll
          for (int u = 0; u < 8; u++)
            acc[t][u] = fmaf(pa, (float)v0[u], acc[t][u]);
        }
      }
    }
    __syncthreads();   // before next chunk overwrites ws/pw
  }

  // write out (B pre-holds the skip term); 8 lanes cover one dst row
#pragma unroll
  for (int t = 0; t < 2; t++) {
    int dl = 2 * g + t;
    if (dl < ndst) {
      _Float16* bp = (_Float16*)Bh + (size_t)(d0 + dl) * 64 + aj * 8;
      f16x8 old = *(const f16x8*)bp;
      float inv = 1.f / (den[t] + 1e-16f);
      f16x8 o;
#pragma unroll
      for (int u = 0; u < 8; u++)
        o[u] = (_Float16)((float)old[u] + acc[t][u] * inv);
      *(f16x8*)bp = o;
    }
  }
}

// ---------------- pooling ----------------
__global__ __launch_bounds__(256) void k_pool(
    const __half* __restrict__ H, const int* __restrict__ batch,
    float* __restrict__ pooled, int* __restrict__ cnt, int n) {
  int lane = threadIdx.x & 63;
  int w = threadIdx.x >> 6;
  int n0 = blockIdx.x * 64 + w * 16;
  float acc = 0.f;
  int cur = -1, nc = 0;
  for (int i = 0; i < 16; i++) {
    int node = n0 + i;
    if (node >= n) break;
    int g = batch[node];
    if (g != cur) {
      if (cur >= 0) {
        atomicAdd(&pooled[cur * 64 + lane], acc);
        if (lane == 0) atomicAdd(&cnt[cur], nc);
      }
      cur = g;
      acc = 0.f;
      nc = 0;
    }
    acc += __half2float(H[(size_t)node * 64 + lane]);
    nc++;
  }
  if (cur >= 0) {
    atomicAdd(&pooled[cur * 64 + lane], acc);
    if (lane == 0) atomicAdd(&cnt[cur], nc);
  }
}

__global__ void k_out(const float* __restrict__ pooled, const int* __restrict__ cnt,
                      const float* __restrict__ Wf, const float* __restrict__ bf,
                      float* __restrict__ out) {
  int g = blockIdx.x;
  int lane = threadIdx.x;
  int c = cnt[g];
  float cf = (float)(c > 1 ? c : 1);
  float mean = pooled[g * 64 + lane] / cf;
#pragma unroll
  for (int o = 0; o < OUTF; o++) {
    float p = wave_reduce_sum(mean * Wf[lane * OUTF + o]);
    if (lane == 0) out[g * OUTF + o] = p + bf[o];
  }
}

// ---------------- launch ----------------
extern "C" void kernel_launch(void* const* d_in, const int* in_sizes, int n_in,
                              void* d_out, int out_size, void* d_ws, size_t ws_size,
                              hipStream_t stream) {
  const float* x   = (const float*)d_in[0];
  const int* ei    = (const int*)d_in[1];
  const int* batch = (const int*)d_in[2];
  const float *Wq0 = (const float*)d_in[3],  *bq0 = (const float*)d_in[4];
  const float *Wk0 = (const float*)d_in[5],  *bk0 = (const float*)d_in[6];
  const float *Wv0 = (const float*)d_in[7],  *bv0 = (const float*)d_in[8];
  const float *Ws0 = (const float*)d_in[9],  *bs0 = (const float*)d_in[10];
  const float *Wqh = (const float*)d_in[11], *bqh = (const float*)d_in[12];
  const float *Wkh = (const float*)d_in[13], *bkh = (const float*)d_in[14];
  const float *Wvh = (const float*)d_in[15], *bvh = (const float*)d_in[16];
  const float *Wsh = (const float*)d_in[17], *bsh = (const float*)d_in[18];
  const float *Wf  = (const float*)d_in[19], *bf  = (const float*)d_in[20];

  __half* qh = (__half*)d_ws;
  __half* kh = qh + (size_t)NN * 64;
  __half* vh = kh + (size_t)NN * 64;
  __half* B0 = vh + (size_t)NN * 64;
  __half* B1 = B0 + (size_t)NN * 64;
  float* pooled = (float*)(B1 + (size_t)NN * 64);
  int* cnt     = (int*)(pooled + GG * 64);
  int* row_ptr = cnt + GG;
  int* col     = row_ptr + NN + 2;
  int* hblk    = col + EE;
  int* incl2   = hblk + LEN;
  int* bsum2   = incl2 + LEN;
  int* boff2   = bsum2 + 128;
  int* eoff    = boff2 + 128;
  int2* ebuf   = (int2*)((((uintptr_t)(eoff + LEN)) + 15) & ~(uintptr_t)15);

  hipMemsetAsync(pooled, 0, (GG * 64 + GG) * sizeof(float), stream);

  // bucketed CSR build (once per call; reused by all 4 layers)
  k_bh<<<EB, 256, 0, stream>>>(ei, hblk);
  int nb2 = (LEN + 1023) / 1024;
  k_scan1<<<nb2, 256, 0, stream>>>(hblk, incl2, bsum2, LEN);
  k_eoff<<<(LEN + 255) / 256, 256, 0, stream>>>(incl2, bsum2, hblk, eoff, LEN, nb2);
  k_binwrite<<<EB, 256, 0, stream>>>(ei, eoff, ebuf);
  k_bcsr<<<NBUK, 256, 0, stream>>>(ebuf, eoff, row_ptr, col, NN);

  int gg = (NN + 127) / 128;            // 2 node-tiles per block (R27)
  int ga = (NN + FB_DST - 1) / FB_DST;  // 32 dsts per block, 128 threads

  // layer 0 (F_IN=16, fp32 input)
  k_gemm_mfma<FIN, float><<<gg, 256, 0, stream>>>(
      x, Wq0, bq0, Wk0, bk0, Wv0, bv0, Ws0, bs0, qh, kh, vh, B0, NN);
  k_fused<<<ga, 128, 0, stream>>>(qh, kh, vh, row_ptr, col, B0, NN);

  // hidden layers (H=64, fp16 h), ping-pong B0 <-> B1
  const __half* hin = B0;
  __half* hout = B1;
  for (int i = 0; i < NHID; i++) {
    k_gemm_mfma<HH, __half><<<gg, 256, 0, stream>>>(
        hin, Wqh + i * 4096, bqh + i * 64,
        Wkh + i * 4096, bkh + i * 64,
        Wvh + i * 4096, bvh + i * 64,
        Wsh + i * 4096, bsh + i * 64,
        qh, kh, vh, hout, NN);
    k_fused<<<ga, 128, 0, stream>>>(qh, kh, vh, row_ptr, col, hout, NN);
    __half* t = (__half*)hin; hin = hout; hout = t;
  }

  k_pool<<<(NN + 63) / 64, 256, 0, stream>>>(hin, batch, pooled, cnt, NN);
  k_out<<<GG, 64, 0, stream>>>(pooled, cnt, Wf, bf, (float*)d_out);
}

// Round 14
// 421.628 us; speedup vs baseline: 1.0747x; 1.0269x over previous
//
#include <hip/hip_runtime.h>
#include <hip/hip_fp16.h>
#include <math.h>
#include <stdint.h>
#include <type_traits>

#define NN   100000
#define EE   1200000
#define GG   128
#define FIN  16
#define HH   64
#define OUTF 5
#define NHID 3

#define CE   4096                       // edges per block in bucket phases
#define EB   ((EE + CE - 1) / CE)       // 293 edge-blocks
#define NBUK ((NN + 511) >> 9)          // 196 buckets of 512 nodes
#define LEN  (NBUK * EB)                // hblk/eoff length

#define SRCMASK 0x03FFFFFFu             // low 26 bits of packed col entry
#define FB_DST 32                       // dsts per fused block

typedef _Float16 f16x8 __attribute__((ext_vector_type(8)));
typedef _Float16 f16x2 __attribute__((ext_vector_type(2)));
typedef float f32x4 __attribute__((ext_vector_type(4)));

#if defined(__has_builtin)
#if __has_builtin(__builtin_amdgcn_fdot2)
#define HAVE_FDOT2 1
#endif
#endif

static __device__ __forceinline__ float dot8_f16(f16x8 a, f16x8 b) {
#ifdef HAVE_FDOT2
  float ds = 0.f;
#pragma unroll
  for (int u = 0; u < 4; u++) {
    f16x2 x = {a[2 * u], a[2 * u + 1]};
    f16x2 y = {b[2 * u], b[2 * u + 1]};
    ds = __builtin_amdgcn_fdot2(x, y, ds, false);
  }
  return ds;
#else
  float ds = 0.f;
#pragma unroll
  for (int u = 0; u < 8; u++) ds += (float)a[u] * (float)b[u];
  return ds;
#endif
}

// ---------------- wave helpers ----------------
static __device__ __forceinline__ float wave_reduce_sum(float p) {
#pragma unroll
  for (int m = 32; m >= 1; m >>= 1) p += __shfl_xor(p, m, 64);
  return p;
}

// ---------------- bucketed CSR build ----------------
__global__ void k_bh(const int* __restrict__ ei, int* __restrict__ hblk) {
  __shared__ int h[NBUK];
  int tid = threadIdx.x, blk = blockIdx.x;
  for (int i = tid; i < NBUK; i += 256) h[i] = 0;
  __syncthreads();
  int base = blk * CE;
  for (int i = tid; i < CE; i += 256) {
    int e = base + i;
    if (e < EE) atomicAdd(&h[ei[EE + e] >> 9], 1);
  }
  __syncthreads();
  for (int i = tid; i < NBUK; i += 256) hblk[i * EB + blk] = h[i];
}

__global__ void k_scan1(const int* __restrict__ in, int* __restrict__ incl,
                        int* __restrict__ bsum, int n) {
  __shared__ int sd[256];
  int t = threadIdx.x, blk = blockIdx.x;
  int base = blk * 1024 + t * 4;
  int v[4];
#pragma unroll
  for (int i = 0; i < 4; i++) v[i] = (base + i < n) ? in[base + i] : 0;
  int s = v[0] + v[1] + v[2] + v[3];
  sd[t] = s;
  __syncthreads();
  for (int off = 1; off < 256; off <<= 1) {
    int x = 0;
    if (t >= off) x = sd[t - off];
    __syncthreads();
    if (t >= off) sd[t] += x;
    __syncthreads();
  }
  int run = sd[t] - s;
#pragma unroll
  for (int i = 0; i < 4; i++) {
    run += v[i];
    if (base + i < n) incl[base + i] = run;
  }
  if (t == 255) bsum[blk] = sd[255];
}

// scan2 folded in (R26-keeper): wave 0 computes the 57-entry exclusive
// prefix of bsum via __shfl_up — replaces the serial k_scan2 dispatch.
__global__ void k_eoff(const int* __restrict__ incl, const int* __restrict__ bsum,
                       const int* __restrict__ hblk, int* __restrict__ eoff,
                       int n, int nb) {
  __shared__ int sb[64];
  int tid = threadIdx.x;
  if (tid < 64) {
    int v = (tid < nb) ? bsum[tid] : 0;
    int x = v;
#pragma unroll
    for (int off = 1; off < 64; off <<= 1) {
      int y = __shfl_up(x, off, 64);
      if (tid >= off) x += y;
    }
    sb[tid] = x - v;                   // exclusive prefix
  }
  __syncthreads();
  int t = blockIdx.x * blockDim.x + tid;
  if (t < n) eoff[t] = incl[t] + sb[t / 1024] - hblk[t];
}

__global__ void k_binwrite(const int* __restrict__ ei, const int* __restrict__ eoff,
                           int2* __restrict__ ebuf) {
  __shared__ int cur[NBUK];
  int tid = threadIdx.x, blk = blockIdx.x;
  for (int i = tid; i < NBUK; i += 256) cur[i] = eoff[i * EB + blk];
  __syncthreads();
  int base = blk * CE;
  for (int i = tid; i < CE; i += 256) {
    int e = base + i;
    if (e < EE) {
      int d = ei[EE + e];
      int s = ei[e];
      int p = atomicAdd(&cur[d >> 9], 1);
      ebuf[p] = make_int2(s, d);
    }
  }
}

// merged bdeg2 + binscatter: histogram -> scan -> row_ptr -> cursors ->
// scatter col. col entry packs dst-mod-64 into bits 26..31 (unused by the
// fused kernel, masked off harmlessly); src (<2^26) in low bits.
__global__ void k_bcsr(const int2* __restrict__ ebuf, const int* __restrict__ eoff,
                       int* __restrict__ row_ptr, int* __restrict__ col, int n) {
  __shared__ int dl[512];
  __shared__ int ps[256];
  int b = blockIdx.x, tid = threadIdx.x;
  int d0 = b << 9;
  dl[tid] = 0; dl[tid + 256] = 0;
  __syncthreads();
  int s0 = eoff[b * EB];
  int s1 = (b + 1 < NBUK) ? eoff[(b + 1) * EB] : EE;
  for (int e = s0 + tid; e < s1; e += 256) atomicAdd(&dl[ebuf[e].y - d0], 1);
  __syncthreads();
  int a0 = dl[2 * tid], a1 = dl[2 * tid + 1];
  ps[tid] = a0 + a1;
  __syncthreads();
  for (int off = 1; off < 256; off <<= 1) {
    int x = 0;
    if (tid >= off) x = ps[tid - off];
    __syncthreads();
    if (tid >= off) ps[tid] += x;
    __syncthreads();
  }
  int epair = ps[tid] - (a0 + a1);     // exclusive prefix of this pair
  int r0 = s0 + epair;
  int r1 = r0 + a0;
  int i0 = d0 + 2 * tid;
  if (i0 <= n) row_ptr[i0] = r0;       // covers row_ptr[n] = EE
  if (i0 + 1 <= n) row_ptr[i0 + 1] = r1;
  __syncthreads();
  dl[2 * tid] = r0;                    // reuse histogram LDS as cursors
  dl[2 * tid + 1] = r1;
  __syncthreads();
  for (int e = s0 + tid; e < s1; e += 256) {
    int2 sd = ebuf[e];
    int p = atomicAdd(&dl[sd.y - d0], 1);
    col[p] = (int)(((unsigned)sd.x) | (((unsigned)sd.y & 63u) << 26));
  }
}

// ---------------- projections via MFMA (R25-exact: best-measured) -----------
// Single 64-node tile per block (R27's 2-tile variant cost ~12us residue:
// 782 blocks = 3/CU lost more parallelism than weight-amortization gained).
// Per-wave private LDS out-staging epilogue (R25): 1KB contiguous stores.
template <int F, typename TIN>
__global__ __launch_bounds__(256) void k_gemm_mfma(
    const TIN* __restrict__ X,
    const float* __restrict__ Wq, const float* __restrict__ bq,
    const float* __restrict__ Wk, const float* __restrict__ bk,
    const float* __restrict__ Wv, const float* __restrict__ bv,
    const float* __restrict__ Ws, const float* __restrict__ bs,
    __half* __restrict__ qh, __half* __restrict__ kh, __half* __restrict__ vh,
    __half* __restrict__ Bh, int n) {
  constexpr int KH = (F + 31) / 32;
  constexpr int S = KH * 32 + 8;
  constexpr int STG = 64 * S;
  constexpr int OUTL = 4 * 16 * 68;        // 4 waves x private 16x68
  constexpr int LSZ = (STG > OUTL) ? STG : OUTL;
  __shared__ _Float16 xs[LSZ];
  int tid = threadIdx.x;
  int lane = tid & 63;
  int wv = tid >> 6;
  int quad = lane >> 4;
  int li = lane & 15;
  int node0 = blockIdx.x * 64;

  if constexpr (std::is_same<TIN, float>::value) {
    constexpr int F4 = F / 4;
    constexpr int CNT = 64 * F4 / 256;
#pragma unroll
    for (int i = 0; i < CNT; i++) {
      int idx = tid + i * 256;
      int nd = idx / F4;
      int kb = (idx % F4) * 4;
      float4 p;
      if (node0 + nd < n) p = *(const float4*)(X + (size_t)(node0 + nd) * F + kb);
      else p = make_float4(0.f, 0.f, 0.f, 0.f);
      _Float16* d = xs + nd * S + kb;
      d[0] = (_Float16)p.x; d[1] = (_Float16)p.y;
      d[2] = (_Float16)p.z; d[3] = (_Float16)p.w;
    }
    if (F == 16) {  // zero-pad k in [16,32)
      int nd = tid >> 2;
      int kb = 16 + (tid & 3) * 4;
      _Float16* d = xs + nd * S + kb;
      d[0] = 0; d[1] = 0; d[2] = 0; d[3] = 0;
    }
  } else {
    constexpr int F8 = F / 8;
    constexpr int CNT = 64 * F8 / 256;
#pragma unroll
    for (int i = 0; i < CNT; i++) {
      int idx = tid + i * 256;
      int nd = idx / F8;
      int kb = (idx % F8) * 8;
      f16x8 p = {};
      if (node0 + nd < n)
        p = *(const f16x8*)((const _Float16*)X + (size_t)(node0 + nd) * F + kb);
      *(f16x8*)(xs + nd * S + kb) = p;
    }
  }

  const float* W; const float* bias;
  if (wv == 0)      { W = Wq; bias = bq; }
  else if (wv == 1) { W = Wk; bias = bk; }
  else if (wv == 2) { W = Wv; bias = bv; }
  else              { W = Ws; bias = bs; }

  f16x8 bf[4][KH];
#pragma unroll
  for (int ns = 0; ns < 4; ns++)
#pragma unroll
    for (int kh2 = 0; kh2 < KH; kh2++)
#pragma unroll
      for (int j = 0; j < 8; j++) {
        int kidx = kh2 * 32 + quad * 8 + j;
        bf[ns][kh2][j] = (kidx < F)
            ? (_Float16)W[(size_t)kidx * 64 + ns * 16 + li] : (_Float16)0.f;
      }
  float blv[4];
#pragma unroll
  for (int ns = 0; ns < 4; ns++) blv[ns] = bias[ns * 16 + li];

  __syncthreads();

  f16x8 af[4][KH];
#pragma unroll
  for (int ms = 0; ms < 4; ms++)
#pragma unroll
    for (int kh2 = 0; kh2 < KH; kh2++)
      af[ms][kh2] = *(const f16x8*)(xs + (ms * 16 + li) * S + kh2 * 32 + quad * 8);

  f32x4 acc[4][4];
#pragma unroll
  for (int ms = 0; ms < 4; ms++)
#pragma unroll
    for (int ns = 0; ns < 4; ns++) {
      float b = blv[ns];
      acc[ms][ns] = (f32x4){b, b, b, b};
    }
#pragma unroll
  for (int kh2 = 0; kh2 < KH; kh2++)
#pragma unroll
    for (int ms = 0; ms < 4; ms++)
#pragma unroll
      for (int ns = 0; ns < 4; ns++)
        acc[ms][ns] = __builtin_amdgcn_mfma_f32_16x16x32_f16(
            af[ms][kh2], bf[ns][kh2], acc[ms][ns], 0, 0, 0);

  __syncthreads();   // end of xs (af) reads; out-staging regions now safe

  __half* outh = (wv == 0) ? qh : (wv == 1) ? kh : (wv == 2) ? vh : Bh;
  _Float16* ob = xs + wv * (16 * 68);   // per-wave private region
#pragma unroll
  for (int ms = 0; ms < 4; ms++) {
#pragma unroll
    for (int ns = 0; ns < 4; ns++)
#pragma unroll
      for (int r = 0; r < 4; r++)
        ob[(quad * 4 + r) * 68 + ns * 16 + li] = (_Float16)acc[ms][ns][r];
#pragma unroll
    for (int it = 0; it < 2; it++) {
      int c = lane + it * 64;
      int row = c >> 3, j = c & 7;
      int node = node0 + ms * 16 + row;
      if (node < n)
        *(f16x8*)((_Float16*)outh + (size_t)node * 64 + j * 8) =
            *(const f16x8*)(ob + row * 68 + j * 8);
    }
  }
}

// ---------------- fused attention, phase-split pair-unroll (R24-exact) ------
// Best-measured structure (44.6us): 2 dsts per 8-lane group, q+acc in
// registers, K-pass / barrier / V-pass phase split (L2 sees one array at
// a time), pair unroll (x4 regressed: VGPR/schedule).
__global__ __launch_bounds__(128) void k_fused(
    const __half* __restrict__ qh, const __half* __restrict__ kh,
    const __half* __restrict__ vh, const int* __restrict__ row_ptr,
    const int* __restrict__ col, __half* __restrict__ Bh, int n) {
  __shared__ int ws[1024];
  __shared__ float pw[1024];
  __shared__ int rpl[FB_DST + 1];
  int tid = threadIdx.x;
  int d0 = blockIdx.x * FB_DST;
  int ndst = n - d0; if (ndst > FB_DST) ndst = FB_DST;

  if (tid < FB_DST + 1) {
    int dd = d0 + tid; if (dd > n) dd = n;
    rpl[tid] = row_ptr[dd];
  }
  __syncthreads();
  int e0 = rpl[0], e1 = rpl[ndst];

  int g = tid >> 3, aj = tid & 7;     // 16 groups x 8 lanes

  f16x8 qv[2] = {};
  float acc[2][8];
  float den[2];
#pragma unroll
  for (int t = 0; t < 2; t++) {
    den[t] = 0.f;
#pragma unroll
    for (int u = 0; u < 8; u++) acc[t][u] = 0.f;
    int dl = 2 * g + t;
    if (dl < ndst)
      qv[t] = *(const f16x8*)((const _Float16*)qh + (size_t)(d0 + dl) * 64 + aj * 8);
  }

  for (int c0 = e0; c0 < e1; c0 += 1024) {
    int cn = e1 - c0; if (cn > 1024) cn = 1024;
#pragma unroll
    for (int s = 0; s < 8; s++) {      // stage col chunk, coalesced
      int i = tid + s * 128;
      if (i < cn) ws[i] = col[c0 + i];
    }
    __syncthreads();

    // ---- K-pass: k-gathers only -> pe, den, pw ----
#pragma unroll
    for (int t = 0; t < 2; t++) {
      int dl = 2 * g + t;
      if (dl < ndst) {
        int lo = rpl[dl];     if (lo < c0) lo = c0;
        int hi = rpl[dl + 1]; int ce = c0 + cn; if (hi > ce) hi = ce;
        int i = lo - c0, iend = hi - c0;
        for (; i + 2 <= iend; i += 2) {
          int s0 = ws[i] & (int)SRCMASK;
          int s1 = ws[i + 1] & (int)SRCMASK;
          f16x8 k0 = *(const f16x8*)((const _Float16*)kh + (size_t)s0 * 64 + aj * 8);
          f16x8 k1 = *(const f16x8*)((const _Float16*)kh + (size_t)s1 * 64 + aj * 8);
          float da = dot8_f16(qv[t], k0);
          float db = dot8_f16(qv[t], k1);
          da += __shfl_xor(da, 1, 64); db += __shfl_xor(db, 1, 64);
          da += __shfl_xor(da, 2, 64); db += __shfl_xor(db, 2, 64);
          da += __shfl_xor(da, 4, 64); db += __shfl_xor(db, 4, 64);
          float pa = __expf(fminf(da * 0.125f, 60.f));   // 1/sqrt(64)
          float pb = __expf(fminf(db * 0.125f, 60.f));
          den[t] += pa + pb;
          if (aj == 0) { pw[i] = pa; pw[i + 1] = pb; }
        }
        if (i < iend) {
          int s0 = ws[i] & (int)SRCMASK;
          f16x8 k0 = *(const f16x8*)((const _Float16*)kh + (size_t)s0 * 64 + aj * 8);
          float da = dot8_f16(qv[t], k0);
          da += __shfl_xor(da, 1, 64);
          da += __shfl_xor(da, 2, 64);
          da += __shfl_xor(da, 4, 64);
          float pa = __expf(fminf(da * 0.125f, 60.f));
          den[t] += pa;
          if (aj == 0) pw[i] = pa;
        }
      }
    }
    __syncthreads();   // phase the gather streams (locality, not correctness)

    // ---- V-pass: v-gathers only; pw broadcast reads; fma into registers ----
#pragma unroll
    for (int t = 0; t < 2; t++) {
      int dl = 2 * g + t;
      if (dl < ndst) {
        int lo = rpl[dl];     if (lo < c0) lo = c0;
        int hi = rpl[dl + 1]; int ce = c0 + cn; if (hi > ce) hi = ce;
        int i = lo - c0, iend = hi - c0;
        for (; i + 2 <= iend; i += 2) {
          int s0 = ws[i] & (int)SRCMASK;
          int s1 = ws[i + 1] & (int)SRCMASK;
          float pa = pw[i], pb = pw[i + 1];
          f16x8 v0 = *(const f16x8*)((const _Float16*)vh + (size_t)s0 * 64 + aj * 8);
          f16x8 v1 = *(const f16x8*)((const _Float16*)vh + (size_t)s1 * 64 + aj * 8);
#pragma unroll
          for (int u = 0; u < 8; u++) {
            acc[t][u] = fmaf(pa, (float)v0[u], acc[t][u]);
            acc[t][u] = fmaf(pb, (float)v1[u], acc[t][u]);
          }
        }
        if (i < iend) {
          int s0 = ws[i] & (int)SRCMASK;
          float pa = pw[i];
          f16x8 v0 = *(const f16x8*)((const _Float16*)vh + (size_t)s0 * 64 + aj * 8);
#pragma unroll
          for (int u = 0; u < 8; u++)
            acc[t][u] = fmaf(pa, (float)v0[u], acc[t][u]);
        }
      }
    }
    __syncthreads();   // before next chunk overwrites ws/pw
  }

  // write out (B pre-holds the skip term); 8 lanes cover one dst row
#pragma unroll
  for (int t = 0; t < 2; t++) {
    int dl = 2 * g + t;
    if (dl < ndst) {
      _Float16* bp = (_Float16*)Bh + (size_t)(d0 + dl) * 64 + aj * 8;
      f16x8 old = *(const f16x8*)bp;
      float inv = 1.f / (den[t] + 1e-16f);
      f16x8 o;
#pragma unroll
      for (int u = 0; u < 8; u++)
        o[u] = (_Float16)((float)old[u] + acc[t][u] * inv);
      *(f16x8*)bp = o;
    }
  }
}

// ---------------- pooling ----------------
__global__ __launch_bounds__(256) void k_pool(
    const __half* __restrict__ H, const int* __restrict__ batch,
    float* __restrict__ pooled, int* __restrict__ cnt, int n) {
  int lane = threadIdx.x & 63;
  int w = threadIdx.x >> 6;
  int n0 = blockIdx.x * 64 + w * 16;
  float acc = 0.f;
  int cur = -1, nc = 0;
  for (int i = 0; i < 16; i++) {
    int node = n0 + i;
    if (node >= n) break;
    int g = batch[node];
    if (g != cur) {
      if (cur >= 0) {
        atomicAdd(&pooled[cur * 64 + lane], acc);
        if (lane == 0) atomicAdd(&cnt[cur], nc);
      }
      cur = g;
      acc = 0.f;
      nc = 0;
    }
    acc += __half2float(H[(size_t)node * 64 + lane]);
    nc++;
  }
  if (cur >= 0) {
    atomicAdd(&pooled[cur * 64 + lane], acc);
    if (lane == 0) atomicAdd(&cnt[cur], nc);
  }
}

__global__ void k_out(const float* __restrict__ pooled, const int* __restrict__ cnt,
                      const float* __restrict__ Wf, const float* __restrict__ bf,
                      float* __restrict__ out) {
  int g = blockIdx.x;
  int lane = threadIdx.x;
  int c = cnt[g];
  float cf = (float)(c > 1 ? c : 1);
  float mean = pooled[g * 64 + lane] / cf;
#pragma unroll
  for (int o = 0; o < OUTF; o++) {
    float p = wave_reduce_sum(mean * Wf[lane * OUTF + o]);
    if (lane == 0) out[g * OUTF + o] = p + bf[o];
  }
}

// ---------------- launch ----------------
extern "C" void kernel_launch(void* const* d_in, const int* in_sizes, int n_in,
                              void* d_out, int out_size, void* d_ws, size_t ws_size,
                              hipStream_t stream) {
  const float* x   = (const float*)d_in[0];
  const int* ei    = (const int*)d_in[1];
  const int* batch = (const int*)d_in[2];
  const float *Wq0 = (const float*)d_in[3],  *bq0 = (const float*)d_in[4];
  const float *Wk0 = (const float*)d_in[5],  *bk0 = (const float*)d_in[6];
  const float *Wv0 = (const float*)d_in[7],  *bv0 = (const float*)d_in[8];
  const float *Ws0 = (const float*)d_in[9],  *bs0 = (const float*)d_in[10];
  const float *Wqh = (const float*)d_in[11], *bqh = (const float*)d_in[12];
  const float *Wkh = (const float*)d_in[13], *bkh = (const float*)d_in[14];
  const float *Wvh = (const float*)d_in[15], *bvh = (const float*)d_in[16];
  const float *Wsh = (const float*)d_in[17], *bsh = (const float*)d_in[18];
  const float *Wf  = (const float*)d_in[19], *bf  = (const float*)d_in[20];

  __half* qh = (__half*)d_ws;
  __half* kh = qh + (size_t)NN * 64;
  __half* vh = kh + (size_t)NN * 64;
  __half* B0 = vh + (size_t)NN * 64;
  __half* B1 = B0 + (size_t)NN * 64;
  float* pooled = (float*)(B1 + (size_t)NN * 64);
  int* cnt     = (int*)(pooled + GG * 64);
  int* row_ptr = cnt + GG;
  int* col     = row_ptr + NN + 2;
  int* hblk    = col + EE;
  int* incl2   = hblk + LEN;
  int* bsum2   = incl2 + LEN;
  int* boff2   = bsum2 + 128;
  int* eoff    = boff2 + 128;
  int2* ebuf   = (int2*)((((uintptr_t)(eoff + LEN)) + 15) & ~(uintptr_t)15);

  hipMemsetAsync(pooled, 0, (GG * 64 + GG) * sizeof(float), stream);

  // bucketed CSR build (once per call; reused by all 4 layers)
  k_bh<<<EB, 256, 0, stream>>>(ei, hblk);
  int nb2 = (LEN + 1023) / 1024;
  k_scan1<<<nb2, 256, 0, stream>>>(hblk, incl2, bsum2, LEN);
  k_eoff<<<(LEN + 255) / 256, 256, 0, stream>>>(incl2, bsum2, hblk, eoff, LEN, nb2);
  k_binwrite<<<EB, 256, 0, stream>>>(ei, eoff, ebuf);
  k_bcsr<<<NBUK, 256, 0, stream>>>(ebuf, eoff, row_ptr, col, NN);

  int gg = (NN + 63) / 64;
  int ga = (NN + FB_DST - 1) / FB_DST;  // 32 dsts per block, 128 threads

  // layer 0 (F_IN=16, fp32 input)
  k_gemm_mfma<FIN, float><<<gg, 256, 0, stream>>>(
      x, Wq0, bq0, Wk0, bk0, Wv0, bv0, Ws0, bs0, qh, kh, vh, B0, NN);
  k_fused<<<ga, 128, 0, stream>>>(qh, kh, vh, row_ptr, col, B0, NN);

  // hidden layers (H=64, fp16 h), ping-pong B0 <-> B1
  const __half* hin = B0;
  __half* hout = B1;
  for (int i = 0; i < NHID; i++) {
    k_gemm_mfma<HH, __half><<<gg, 256, 0, stream>>>(
        hin, Wqh + i * 4096, bqh + i * 64,
        Wkh + i * 4096, bkh + i * 64,
        Wvh + i * 4096, bvh + i * 64,
        Wsh + i * 4096, bsh + i * 64,
        qh, kh, vh, hout, NN);
    k_fused<<<ga, 128, 0, stream>>>(qh, kh, vh, row_ptr, col, hout, NN);
    __half* t = (__half*)hin; hin = hout; hout = t;
  }

  k_pool<<<(NN + 63) / 64, 256, 0, stream>>>(hin, batch, pooled, cnt, NN);
  k_out<<<GG, 64, 0, stream>>>(pooled, cnt, Wf, bf, (float*)d_out);
}